// Round 2
// baseline (556258.301 us; speedup 1.0000x reference)
//
#include <hip/hip_runtime.h>

#define TT 1024
#define BB 64
#define HH 512
#define DD 512
#define G4H 2048
#define NBLK 256
#define NTHR 256

// ws layout (floats)
#define WS_H0 0
#define WS_C0 32768
#define WS_H1 65536
#define WS_C1 98304
#define WS_Z0P 131072                      // 16*64*2048 = 2097152
#define WS_Z1P (131072 + 2097152)          // 16*64*2048
#define WS_HWZ (131072 + 2*2097152)        // 8*64*512  = 262144
#define WS_BAR (WS_HWZ + 262144)           // barrier: cnt @ +0, gen @ +32 (separate lines)

// ---------------- manual grid barrier (persistent kernel, 256 resident blocks) -------
// Correctness notes:
//  * agent-scope atomics: cross-XCD L2s are non-coherent; sc1 ops hit the coherent point.
//  * __threadfence() before arrive publishes this block's global writes; after wait,
//    acquires other blocks' writes.
//  * gen re-read staleness is impossible: same-location read-read coherence + gen can't
//    advance past this block's last observed value until this block arrives.
__device__ __forceinline__ void grid_sync(unsigned* bar)
{
    __syncthreads();
    __threadfence();
    if (threadIdx.x == 0) {
        unsigned* cnt = bar;
        unsigned* gen = bar + 8;           // 32B apart -> different dwords/lines
        unsigned g = __hip_atomic_load(gen, __ATOMIC_RELAXED, __HIP_MEMORY_SCOPE_AGENT);
        unsigned a = __hip_atomic_fetch_add(cnt, 1u, __ATOMIC_ACQ_REL, __HIP_MEMORY_SCOPE_AGENT);
        if (a == NBLK - 1u) {
            __hip_atomic_store(cnt, 0u, __ATOMIC_RELAXED, __HIP_MEMORY_SCOPE_AGENT);
            __hip_atomic_fetch_add(gen, 1u, __ATOMIC_RELEASE, __HIP_MEMORY_SCOPE_AGENT);
        } else {
            while (__hip_atomic_load(gen, __ATOMIC_ACQUIRE, __HIP_MEMORY_SCOPE_AGENT) == g) {
                __builtin_amdgcn_s_sleep(1);
            }
        }
    }
    __threadfence();
    __syncthreads();
}

// ---------------- init: zero recurrent state + barrier words (runs first, each call) --
__global__ void ln_lstm_init_kernel(float* __restrict__ ws)
{
    const int n = 131072;                  // h0,c0,h1,c1
    for (int i = blockIdx.x * blockDim.x + threadIdx.x; i < n; i += gridDim.x * blockDim.x)
        ws[i] = 0.f;
    if (blockIdx.x == 0 && threadIdx.x < 16)
        ((unsigned*)(ws + WS_BAR))[threadIdx.x] = 0u;
}

// ---------------- GEMM tile: 128 rows x 64 K-cols x 64 batch ----------------
__device__ __forceinline__ void gemm_tile(const float* __restrict__ wlds,
                                          const float* __restrict__ inT,
                                          float* __restrict__ dst,
                                          int r0, int tid)
{
    const int rq = tid >> 3;       // 0..31
    const int bq = tid & 7;        // 0..7
    const int r0t = rq * 4;
    const int b0t = bq * 8;
    float acc[4][8];
#pragma unroll
    for (int i = 0; i < 4; ++i)
#pragma unroll
        for (int bb = 0; bb < 8; ++bb) acc[i][bb] = 0.f;

#pragma unroll 4
    for (int kk = 0; kk < 64; kk += 4) {
        float4 wv[4];
#pragma unroll
        for (int i = 0; i < 4; ++i)
            wv[i] = *(const float4*)&wlds[(r0t + i) * 68 + kk];
        float4 av[4][2];
#pragma unroll
        for (int j = 0; j < 4; ++j) {
            av[j][0] = *(const float4*)&inT[(kk + j) * 68 + b0t];
            av[j][1] = *(const float4*)&inT[(kk + j) * 68 + b0t + 4];
        }
#pragma unroll
        for (int j = 0; j < 4; ++j) {
            const float* a = (const float*)&av[j][0];
#pragma unroll
            for (int i = 0; i < 4; ++i) {
                const float w = ((const float*)&wv[i])[j];
#pragma unroll
                for (int bb = 0; bb < 8; ++bb) acc[i][bb] += w * a[bb];
            }
        }
    }
#pragma unroll
    for (int bb = 0; bb < 8; ++bb) {
        float4 v; v.x = acc[0][bb]; v.y = acc[1][bb]; v.z = acc[2][bb]; v.w = acc[3][bb];
        *(float4*)&dst[(size_t)(b0t + bb) * G4H + r0 + r0t] = v;
    }
}

// ---------------- highway tile: 32 rows x 64 K x 64 batch ----------------
__device__ __forceinline__ void hw_tile(const float* __restrict__ whws,
                                        const float* __restrict__ inT,
                                        float* __restrict__ dst,
                                        int r0hw, int tid)
{
    const int rq = tid >> 5;       // 0..7
    const int bq = tid & 31;       // 0..31
    const int r0t = rq * 4;
    const int b0t = bq * 2;
    float acc[4][2];
#pragma unroll
    for (int i = 0; i < 4; ++i) { acc[i][0] = 0.f; acc[i][1] = 0.f; }

#pragma unroll 4
    for (int kk = 0; kk < 64; kk += 4) {
        float4 wv[4];
#pragma unroll
        for (int i = 0; i < 4; ++i)
            wv[i] = *(const float4*)&whws[(r0t + i) * 68 + kk];
        float2 av[4];
#pragma unroll
        for (int j = 0; j < 4; ++j)
            av[j] = *(const float2*)&inT[(kk + j) * 68 + b0t];
#pragma unroll
        for (int j = 0; j < 4; ++j)
#pragma unroll
            for (int i = 0; i < 4; ++i) {
                const float w = ((const float*)&wv[i])[j];
                acc[i][0] += w * av[j].x;
                acc[i][1] += w * av[j].y;
            }
    }
#pragma unroll
    for (int bb = 0; bb < 2; ++bb) {
        float4 v; v.x = acc[0][bb]; v.y = acc[1][bb]; v.z = acc[2][bb]; v.w = acc[3][bb];
        *(float4*)&dst[(size_t)(b0t + bb) * HH + r0hw + r0t] = v;
    }
}

// ---------------- block-wide reduction of two scalars over 256 threads ----------------
__device__ __forceinline__ void block_reduce2(float& s1, float& s2, float* sred, int tid)
{
#pragma unroll
    for (int off = 32; off > 0; off >>= 1) {
        s1 += __shfl_down(s1, off, 64);
        s2 += __shfl_down(s2, off, 64);
    }
    __syncthreads();
    if ((tid & 63) == 0) {
        const int wv = tid >> 6;
        sred[wv] = s1; sred[4 + wv] = s2;
    }
    __syncthreads();
    s1 = sred[0] + sred[1] + sred[2] + sred[3];
    s2 = sred[4] + sred[5] + sred[6] + sred[7];
}

// ---------------- LSTM cell update for one batch row, all LN block-local --------------
__device__ __forceinline__ void cell_update(const float* __restrict__ zp, int nks, size_t kstr,
                                            const float* __restrict__ bias,
                                            const float* __restrict__ lng,
                                            const float* __restrict__ lnb,
                                            float* __restrict__ cb, float* __restrict__ hb,
                                            float* sred, int tid)
{
    float act[4][2];
#pragma unroll
    for (int g = 0; g < 4; ++g) {
        float z[2];
#pragma unroll
        for (int e = 0; e < 2; ++e) {
            const int r = g * 512 + tid + e * 256;
            float s = bias[r];
            for (int ks = 0; ks < nks; ++ks) s += zp[(size_t)ks * kstr + r];
            z[e] = s;
        }
        float s1 = z[0] + z[1];
        float s2 = z[0] * z[0] + z[1] * z[1];
        block_reduce2(s1, s2, sred, tid);
        const float mu = s1 * (1.f / 512.f);
        const float rs = rsqrtf(s2 * (1.f / 512.f) - mu * mu + 1e-5f);
#pragma unroll
        for (int e = 0; e < 2; ++e) {
            const int j = tid + e * 256;
            const float a = (z[e] - mu) * rs * lng[g * 512 + j] + lnb[g * 512 + j];
            act[g][e] = (g == 2) ? tanhf(a) : 1.f / (1.f + expf(-a));
        }
    }
    float cn[2];
#pragma unroll
    for (int e = 0; e < 2; ++e) {
        const int j = tid + e * 256;
        cn[e] = act[1][e] * cb[j] + act[0][e] * act[2][e];
        cb[j] = cn[e];
    }
    float s1 = cn[0] + cn[1];
    float s2 = cn[0] * cn[0] + cn[1] * cn[1];
    block_reduce2(s1, s2, sred, tid);
    const float mu = s1 * (1.f / 512.f);
    const float rs = rsqrtf(s2 * (1.f / 512.f) - mu * mu + 1e-5f);
#pragma unroll
    for (int e = 0; e < 2; ++e) {
        const int j = tid + e * 256;
        const float a = (cn[e] - mu) * rs * lng[4 * 512 + j] + lnb[4 * 512 + j];
        hb[j] = act[3][e] * tanhf(a);
    }
}

__global__ __launch_bounds__(NTHR, 1)
void LayerNormLSTMStack_55508157333865_kernel(
    const float* __restrict__ x,
    const float* __restrict__ W0, const float* __restrict__ b0,
    const float* __restrict__ lng0, const float* __restrict__ lnb0,
    const float* __restrict__ W1, const float* __restrict__ b1,
    const float* __restrict__ lng1, const float* __restrict__ lnb1,
    const float* __restrict__ hwW, const float* __restrict__ hwb,
    float* __restrict__ out, float* __restrict__ ws)
{
    __shared__ float wlds[128 * 68];   // 34816 B
    __shared__ float inT[64 * 68];     // 17408 B
    __shared__ float whws[32 * 68];    //  8704 B  (persistent highway weights)
    __shared__ float sred[8];

    const int tid = threadIdx.x;
    const int blk = blockIdx.x;
    const int rg = blk >> 4;          // 0..15 row-group
    const int kb = blk & 15;          // 0..15 K-slice
    const int r0 = rg * 128;          // GEMM row base

    float* h0 = ws + WS_H0;  float* c0 = ws + WS_C0;
    float* h1 = ws + WS_H1;  float* c1 = ws + WS_C1;
    float* z0p = ws + WS_Z0P; float* z1p = ws + WS_Z1P; float* hwzp = ws + WS_HWZ;
    unsigned* bar = (unsigned*)(ws + WS_BAR);

    // preload highway weight tile once (blocks kb>=8 own hw K-slices); first consumer
    // is t=1 P1, well after the first __syncthreads.
    if (kb >= 8) {
        const int r0hw = rg * 32;
        const int r = tid >> 3, kq = tid & 7;
        const float* src = hwW + (size_t)(r0hw + r) * 512 + (kb - 8) * 64 + kq * 8;
        *(float4*)&whws[r * 68 + kq * 8]     = *(const float4*)(src);
        *(float4*)&whws[r * 68 + kq * 8 + 4] = *(const float4*)(src + 4);
    }

    for (int t = 0; t <= TT; ++t) {
        // ================= P1: gemm0(t) + hw(t-1) + cell1(t-1) =================
        const bool do_g0 = (t < TT);
        const bool do_hw = (t >= 1) && (kb >= 8);
        const bool do_c1 = (t >= 1) && (kb < 4);

        if (do_g0 || do_hw) {
            const int b = tid >> 2, kq = tid & 3;
            const float* src = (kb < 8) ? (x + ((size_t)b * TT + t) * DD + kb * 64)
                                        : (h0 + b * 512 + (kb - 8) * 64);
#pragma unroll
            for (int i = 0; i < 4; ++i) {
                const int kk = kq * 16 + i * 4;
                const float4 v = *(const float4*)(src + kk);
                inT[(kk + 0) * 68 + b] = v.x;
                inT[(kk + 1) * 68 + b] = v.y;
                inT[(kk + 2) * 68 + b] = v.z;
                inT[(kk + 3) * 68 + b] = v.w;
            }
        }
        if (do_g0) {
            const int r = tid >> 1, kq = tid & 1;
            const float* src = W0 + (size_t)(r0 + r) * 1024 + kb * 64 + kq * 32;
#pragma unroll
            for (int i = 0; i < 8; ++i)
                *(float4*)&wlds[r * 68 + kq * 32 + i * 4] = *(const float4*)(src + i * 4);
        }
        __syncthreads();
        if (do_g0) gemm_tile(wlds, inT, z0p + (size_t)kb * 64 * G4H, r0, tid);
        if (do_hw) hw_tile(whws, inT, hwzp + (size_t)(kb - 8) * 64 * HH, rg * 32, tid);
        if (do_c1) {
            const int b = rg * 4 + kb;   // 64 distinct b
            __syncthreads();
            cell_update(z1p + (size_t)b * G4H, 16, (size_t)64 * G4H,
                        b1, lng1, lnb1, c1 + b * 512, h1 + b * 512, sred, tid);
        }
        grid_sync(bar);

        // ================= P2: out(t-1) + cell0(t) (+ final states) =================
        if (kb >= 4 && kb < 8) {
            const int b = rg * 4 + (kb - 4);  // 64 distinct b
            if (t >= 1) {
#pragma unroll
                for (int e = 0; e < 2; ++e) {
                    const int j = tid + e * 256;
                    float s = hwb[j];
                    for (int ks = 0; ks < 8; ++ks)
                        s += hwzp[(size_t)ks * 64 * HH + b * 512 + j];
                    const float gt = 1.f / (1.f + expf(-s));
                    out[((size_t)b * TT + (t - 1)) * HH + j] =
                        gt * h1[b * 512 + j] + (1.f - gt) * h0[b * 512 + j];
                }
            }
            if (t < TT) {
                cell_update(z0p + (size_t)b * G4H, 16, (size_t)64 * G4H,
                            b0, lng0, lnb0, c0 + b * 512, h0 + b * 512, sred, tid);
            } else {
                const size_t OUT_SZ = (size_t)BB * TT * HH;
#pragma unroll
                for (int e = 0; e < 2; ++e) {
                    const int j = tid + e * 256;
                    out[OUT_SZ + b * 512 + j]                 = h0[b * 512 + j];  // h_n[0]
                    out[OUT_SZ + 32768 + b * 512 + j]         = h1[b * 512 + j];  // h_n[1]
                    out[OUT_SZ + 65536 + b * 512 + j]         = c0[b * 512 + j];  // c_n[0]
                    out[OUT_SZ + 65536 + 32768 + b * 512 + j] = c1[b * 512 + j];  // c_n[1]
                }
            }
        }
        grid_sync(bar);
        if (t == TT) break;

        // ================= P3: gemm1(t) =================
        {
            const int b = tid >> 2, kq = tid & 3;
            const float* src = (kb < 8) ? (h0 + b * 512 + kb * 64)
                                        : (h1 + b * 512 + (kb - 8) * 64);
#pragma unroll
            for (int i = 0; i < 4; ++i) {
                const int kk = kq * 16 + i * 4;
                const float4 v = *(const float4*)(src + kk);
                inT[(kk + 0) * 68 + b] = v.x;
                inT[(kk + 1) * 68 + b] = v.y;
                inT[(kk + 2) * 68 + b] = v.z;
                inT[(kk + 3) * 68 + b] = v.w;
            }
            const int r = tid >> 1, kq2 = tid & 1;
            const float* wsrc = W1 + (size_t)(r0 + r) * 1024 + kb * 64 + kq2 * 32;
#pragma unroll
            for (int i = 0; i < 8; ++i)
                *(float4*)&wlds[r * 68 + kq2 * 32 + i * 4] = *(const float4*)(wsrc + i * 4);
            __syncthreads();
            gemm_tile(wlds, inT, z1p + (size_t)kb * 64 * G4H, r0, tid);
        }
        grid_sync(bar);
    }
}

extern "C" void kernel_launch(void* const* d_in, const int* in_sizes, int n_in,
                              void* d_out, int out_size, void* d_ws, size_t ws_size,
                              hipStream_t stream)
{
    (void)in_sizes; (void)n_in; (void)out_size; (void)ws_size;
    const float* x    = (const float*)d_in[0];
    const float* W0   = (const float*)d_in[1];
    const float* b0   = (const float*)d_in[2];
    const float* lng0 = (const float*)d_in[3];
    const float* lnb0 = (const float*)d_in[4];
    const float* W1   = (const float*)d_in[5];
    const float* b1   = (const float*)d_in[6];
    const float* lng1 = (const float*)d_in[7];
    const float* lnb1 = (const float*)d_in[8];
    const float* hwW  = (const float*)d_in[9];
    const float* hwb  = (const float*)d_in[10];
    float* out = (float*)d_out;
    float* ws  = (float*)d_ws;

    ln_lstm_init_kernel<<<dim3(128), dim3(256), 0, stream>>>(ws);
    LayerNormLSTMStack_55508157333865_kernel<<<dim3(NBLK), dim3(NTHR), 0, stream>>>(
        x, W0, b0, lng0, lnb0, W1, b1, lng1, lnb1, hwW, hwb, out, ws);
}

// Round 3
// 136864.722 us; speedup vs baseline: 4.0643x; 4.0643x over previous
//
#include <hip/hip_runtime.h>

#define TT 1024
#define BB 64
#define HH 512
#define DD 512
#define G4H 2048
#define NBLK 256
#define NTHR 256

// ws layout (floats)
#define WS_H0 0
#define WS_C0 32768                        // unused (c0 lives in registers)
#define WS_H1 65536
#define WS_C1 98304                        // c1 mirror (for final-state epilogue)
#define WS_Z0P 131072                      // 16*64*2048 = 2097152
#define WS_Z1P (131072 + 2097152)          // 16*64*2048
#define WS_HWZ (131072 + 2*2097152)        // 8*64*512  = 262144
#define WS_BAR (WS_HWZ + 262144)           // barrier: cnt @ +0, gen @ +32 floats

// ======== coherent (agent-scope, fence-free) global access helpers ========
// Relaxed agent atomics compile to global_load/store with sc1 and NO
// buffer_wbl2/buffer_inv — coherent at the MALL, zero cache-maintenance cost.
__device__ __forceinline__ float ldg_cg(const float* p) {
    return __hip_atomic_load(p, __ATOMIC_RELAXED, __HIP_MEMORY_SCOPE_AGENT);
}
__device__ __forceinline__ void stg_cg(float* p, float v) {
    __hip_atomic_store(p, v, __ATOMIC_RELAXED, __HIP_MEMORY_SCOPE_AGENT);
}
__device__ __forceinline__ float4 ldg_cg4(const float* p) {
    const unsigned long long* q = (const unsigned long long*)p;
    unsigned long long a = __hip_atomic_load(q,     __ATOMIC_RELAXED, __HIP_MEMORY_SCOPE_AGENT);
    unsigned long long b = __hip_atomic_load(q + 1, __ATOMIC_RELAXED, __HIP_MEMORY_SCOPE_AGENT);
    float4 v;
    ((unsigned long long*)&v)[0] = a;
    ((unsigned long long*)&v)[1] = b;
    return v;
}
__device__ __forceinline__ void stg_cg4(float* p, float4 v) {
    unsigned long long* q = (unsigned long long*)p;
    __hip_atomic_store(q,     ((unsigned long long*)&v)[0], __ATOMIC_RELAXED, __HIP_MEMORY_SCOPE_AGENT);
    __hip_atomic_store(q + 1, ((unsigned long long*)&v)[1], __ATOMIC_RELAXED, __HIP_MEMORY_SCOPE_AGENT);
}

// ======== fence-free grid barrier (persistent kernel, 256 resident blocks) ========
// Monotonic arrival counter (no reset) + generation word. All data ordering is
// real-time: __syncthreads drains vmcnt(0) so this block's sc1 stores are at the
// coherence point before the arrival add; consumers' sc1 loads read the coherence
// point after observing the generation bump. No acquire/release -> no L2 flushes.
__device__ __forceinline__ void grid_sync(unsigned* bar, unsigned ph)
{
    __syncthreads();
    if (threadIdx.x == 0) {
        unsigned* cnt = bar;
        unsigned* gen = bar + 32;          // 128 B apart
        unsigned a = __hip_atomic_fetch_add(cnt, 1u, __ATOMIC_RELAXED, __HIP_MEMORY_SCOPE_AGENT);
        if (a == ph * NBLK + (NBLK - 1u)) {
            __hip_atomic_store(gen, ph + 1u, __ATOMIC_RELAXED, __HIP_MEMORY_SCOPE_AGENT);
        } else {
            while (__hip_atomic_load(gen, __ATOMIC_RELAXED, __HIP_MEMORY_SCOPE_AGENT) <= ph) {
                __builtin_amdgcn_s_sleep(1);
            }
        }
    }
    __syncthreads();
}

// ---------------- init: zero h/c state + barrier words (runs first, each call) --------
__global__ void ln_lstm_init_kernel(float* __restrict__ ws)
{
    const int n = 131072;                  // h0,c0,h1,c1 regions
    for (int i = blockIdx.x * blockDim.x + threadIdx.x; i < n; i += gridDim.x * blockDim.x)
        ws[i] = 0.f;
    if (blockIdx.x == 0 && threadIdx.x < 64)
        ((unsigned*)(ws + WS_BAR))[threadIdx.x] = 0u;
}

// ---------------- GEMM tile: 128 rows x 64 K-cols x 64 batch ----------------
__device__ __forceinline__ void gemm_tile(const float* __restrict__ wlds,
                                          const float* __restrict__ inT,
                                          float* __restrict__ dst,
                                          int r0, int tid)
{
    const int rq = tid >> 3;       // 0..31
    const int bq = tid & 7;        // 0..7
    const int r0t = rq * 4;
    const int b0t = bq * 8;
    float acc[4][8];
#pragma unroll
    for (int i = 0; i < 4; ++i)
#pragma unroll
        for (int bb = 0; bb < 8; ++bb) acc[i][bb] = 0.f;

#pragma unroll 4
    for (int kk = 0; kk < 64; kk += 4) {
        float4 wv[4];
#pragma unroll
        for (int i = 0; i < 4; ++i)
            wv[i] = *(const float4*)&wlds[(r0t + i) * 68 + kk];
        float4 av[4][2];
#pragma unroll
        for (int j = 0; j < 4; ++j) {
            av[j][0] = *(const float4*)&inT[(kk + j) * 68 + b0t];
            av[j][1] = *(const float4*)&inT[(kk + j) * 68 + b0t + 4];
        }
#pragma unroll
        for (int j = 0; j < 4; ++j) {
            const float* a = (const float*)&av[j][0];
#pragma unroll
            for (int i = 0; i < 4; ++i) {
                const float w = ((const float*)&wv[i])[j];
#pragma unroll
                for (int bb = 0; bb < 8; ++bb) acc[i][bb] += w * a[bb];
            }
        }
    }
#pragma unroll
    for (int bb = 0; bb < 8; ++bb) {
        float4 v; v.x = acc[0][bb]; v.y = acc[1][bb]; v.z = acc[2][bb]; v.w = acc[3][bb];
        stg_cg4(&dst[(size_t)(b0t + bb) * G4H + r0 + r0t], v);
    }
}

// ---------------- highway tile: 32 rows x 64 K x 64 batch ----------------
__device__ __forceinline__ void hw_tile(const float* __restrict__ whws,
                                        const float* __restrict__ inT,
                                        float* __restrict__ dst,
                                        int r0hw, int tid)
{
    const int rq = tid >> 5;       // 0..7
    const int bq = tid & 31;       // 0..31
    const int r0t = rq * 4;
    const int b0t = bq * 2;
    float acc[4][2];
#pragma unroll
    for (int i = 0; i < 4; ++i) { acc[i][0] = 0.f; acc[i][1] = 0.f; }

#pragma unroll 4
    for (int kk = 0; kk < 64; kk += 4) {
        float4 wv[4];
#pragma unroll
        for (int i = 0; i < 4; ++i)
            wv[i] = *(const float4*)&whws[(r0t + i) * 68 + kk];
        float2 av[4];
#pragma unroll
        for (int j = 0; j < 4; ++j)
            av[j] = *(const float2*)&inT[(kk + j) * 68 + b0t];
#pragma unroll
        for (int j = 0; j < 4; ++j)
#pragma unroll
            for (int i = 0; i < 4; ++i) {
                const float w = ((const float*)&wv[i])[j];
                acc[i][0] += w * av[j].x;
                acc[i][1] += w * av[j].y;
            }
    }
#pragma unroll
    for (int bb = 0; bb < 2; ++bb) {
        float4 v; v.x = acc[0][bb]; v.y = acc[1][bb]; v.z = acc[2][bb]; v.w = acc[3][bb];
        stg_cg4(&dst[(size_t)(b0t + bb) * HH + r0hw + r0t], v);
    }
}

// ---------------- block-wide reduction of two scalars over 256 threads ----------------
__device__ __forceinline__ void block_reduce2(float& s1, float& s2, float* sred, int tid)
{
#pragma unroll
    for (int off = 32; off > 0; off >>= 1) {
        s1 += __shfl_down(s1, off, 64);
        s2 += __shfl_down(s2, off, 64);
    }
    __syncthreads();
    if ((tid & 63) == 0) {
        const int wv = tid >> 6;
        sred[wv] = s1; sred[4 + wv] = s2;
    }
    __syncthreads();
    s1 = sred[0] + sred[1] + sred[2] + sred[3];
    s2 = sred[4] + sred[5] + sred[6] + sred[7];
}

// ---------------- LSTM cell update for one batch row; c kept in registers ------------
__device__ __forceinline__ void cell_update(const float* __restrict__ zp,
                                            const float* __restrict__ bias,
                                            const float* __restrict__ lng,
                                            const float* __restrict__ lnb,
                                            float creg[2], float* __restrict__ c_ws,
                                            float* __restrict__ hb,
                                            float* sred, int tid)
{
    const size_t KSTR = (size_t)64 * G4H;
    float act[4][2];
#pragma unroll
    for (int g = 0; g < 4; ++g) {
        float z[2];
#pragma unroll
        for (int e = 0; e < 2; ++e) {
            const int r = g * 512 + tid + e * 256;
            float s = bias[r];
            for (int ks = 0; ks < 16; ++ks) s += ldg_cg(zp + (size_t)ks * KSTR + r);
            z[e] = s;
        }
        float s1 = z[0] + z[1];
        float s2 = z[0] * z[0] + z[1] * z[1];
        block_reduce2(s1, s2, sred, tid);
        const float mu = s1 * (1.f / 512.f);
        const float rs = rsqrtf(s2 * (1.f / 512.f) - mu * mu + 1e-5f);
#pragma unroll
        for (int e = 0; e < 2; ++e) {
            const int j = tid + e * 256;
            const float a = (z[e] - mu) * rs * lng[g * 512 + j] + lnb[g * 512 + j];
            act[g][e] = (g == 2) ? tanhf(a) : 1.f / (1.f + expf(-a));
        }
    }
    float cn[2];
#pragma unroll
    for (int e = 0; e < 2; ++e) {
        cn[e] = act[1][e] * creg[e] + act[0][e] * act[2][e];
        creg[e] = cn[e];
        if (c_ws) stg_cg(c_ws + tid + e * 256, cn[e]);
    }
    float s1 = cn[0] + cn[1];
    float s2 = cn[0] * cn[0] + cn[1] * cn[1];
    block_reduce2(s1, s2, sred, tid);
    const float mu = s1 * (1.f / 512.f);
    const float rs = rsqrtf(s2 * (1.f / 512.f) - mu * mu + 1e-5f);
#pragma unroll
    for (int e = 0; e < 2; ++e) {
        const int j = tid + e * 256;
        const float a = (cn[e] - mu) * rs * lng[4 * 512 + j] + lnb[4 * 512 + j];
        stg_cg(hb + j, act[3][e] * tanhf(a));
    }
}

__global__ __launch_bounds__(NTHR, 1)
void LayerNormLSTMStack_55508157333865_kernel(
    const float* __restrict__ x,
    const float* __restrict__ W0, const float* __restrict__ b0,
    const float* __restrict__ lng0, const float* __restrict__ lnb0,
    const float* __restrict__ W1, const float* __restrict__ b1,
    const float* __restrict__ lng1, const float* __restrict__ lnb1,
    const float* __restrict__ hwW, const float* __restrict__ hwb,
    float* __restrict__ out, float* __restrict__ ws)
{
    __shared__ float wlds[128 * 68];   // 34816 B
    __shared__ float inT[64 * 68];     // 17408 B
    __shared__ float whws[32 * 68];    //  8704 B  (persistent highway weights)
    __shared__ float sred[8];

    const int tid = threadIdx.x;
    const int blk = blockIdx.x;
    const int rg = blk >> 4;          // 0..15 row-group
    const int kb = blk & 15;          // 0..15 K-slice
    const int r0 = rg * 128;          // GEMM row base

    float* h0 = ws + WS_H0;  float* h1 = ws + WS_H1;  float* c1ws = ws + WS_C1;
    float* z0p = ws + WS_Z0P; float* z1p = ws + WS_Z1P; float* hwzp = ws + WS_HWZ;
    unsigned* bar = (unsigned*)(ws + WS_BAR);

    float creg[2] = {0.f, 0.f};       // c-state for whichever cell role this block has
    unsigned ph = 0;

    // preload highway weight tile once (blocks kb>=8 own hw K-slices)
    if (kb >= 8) {
        const int r0hw = rg * 32;
        const int r = tid >> 3, kq = tid & 7;
        const float* src = hwW + (size_t)(r0hw + r) * 512 + (kb - 8) * 64 + kq * 8;
        *(float4*)&whws[r * 68 + kq * 8]     = *(const float4*)(src);
        *(float4*)&whws[r * 68 + kq * 8 + 4] = *(const float4*)(src + 4);
    }

    for (int t = 0; t <= TT; ++t) {
        // ================= P1: gemm0(t) + hw(t-1) + cell1(t-1) =================
        const bool do_g0 = (t < TT);
        const bool do_hw = (t >= 1) && (kb >= 8);
        const bool do_c1 = (t >= 1) && (kb < 4);

        if (do_g0 || do_hw) {
            const int b = tid >> 2, kq = tid & 3;
#pragma unroll
            for (int i = 0; i < 4; ++i) {
                const int kk = kq * 16 + i * 4;
                const float4 v = (kb < 8)
                    ? *(const float4*)(x + ((size_t)b * TT + t) * DD + kb * 64 + kk)
                    : ldg_cg4(h0 + b * 512 + (kb - 8) * 64 + kk);
                inT[(kk + 0) * 68 + b] = v.x;
                inT[(kk + 1) * 68 + b] = v.y;
                inT[(kk + 2) * 68 + b] = v.z;
                inT[(kk + 3) * 68 + b] = v.w;
            }
        }
        if (do_g0) {
            const int r = tid >> 1, kq = tid & 1;
            const float* src = W0 + (size_t)(r0 + r) * 1024 + kb * 64 + kq * 32;
#pragma unroll
            for (int i = 0; i < 8; ++i)
                *(float4*)&wlds[r * 68 + kq * 32 + i * 4] = *(const float4*)(src + i * 4);
        }
        __syncthreads();
        if (do_g0) gemm_tile(wlds, inT, z0p + (size_t)kb * 64 * G4H, r0, tid);
        if (do_hw) hw_tile(whws, inT, hwzp + (size_t)(kb - 8) * 64 * HH, rg * 32, tid);
        if (do_c1) {
            const int b = rg * 4 + kb;   // 64 distinct b
            cell_update(z1p + (size_t)b * G4H, b1, lng1, lnb1,
                        creg, c1ws + b * 512, h1 + b * 512, sred, tid);
        }
        grid_sync(bar, ph++);

        // ================= P2: out(t-1) + cell0(t) (+ final states) =================
        if (kb >= 4 && kb < 8) {
            const int b = rg * 4 + (kb - 4);  // 64 distinct b
            if (t >= 1) {
#pragma unroll
                for (int e = 0; e < 2; ++e) {
                    const int j = tid + e * 256;
                    float s = hwb[j];
                    for (int ks = 0; ks < 8; ++ks)
                        s += ldg_cg(hwzp + (size_t)ks * 64 * HH + b * 512 + j);
                    const float gt = 1.f / (1.f + expf(-s));
                    out[((size_t)b * TT + (t - 1)) * HH + j] =
                        gt * ldg_cg(h1 + b * 512 + j) + (1.f - gt) * ldg_cg(h0 + b * 512 + j);
                }
            }
            if (t < TT) {
                cell_update(z0p + (size_t)b * G4H, b0, lng0, lnb0,
                            creg, (float*)nullptr, h0 + b * 512, sred, tid);
            } else {
                const size_t OUT_SZ = (size_t)BB * TT * HH;
#pragma unroll
                for (int e = 0; e < 2; ++e) {
                    const int j = tid + e * 256;
                    out[OUT_SZ + b * 512 + j]                 = ldg_cg(h0 + b * 512 + j);   // h_n[0]
                    out[OUT_SZ + 32768 + b * 512 + j]         = ldg_cg(h1 + b * 512 + j);   // h_n[1]
                    out[OUT_SZ + 65536 + b * 512 + j]         = creg[e];                     // c_n[0]
                    out[OUT_SZ + 65536 + 32768 + b * 512 + j] = ldg_cg(c1ws + b * 512 + j); // c_n[1]
                }
            }
        }
        grid_sync(bar, ph++);
        if (t == TT) break;

        // ================= P3: gemm1(t) =================
        {
            const int b = tid >> 2, kq = tid & 3;
#pragma unroll
            for (int i = 0; i < 4; ++i) {
                const int kk = kq * 16 + i * 4;
                const float4 v = (kb < 8)
                    ? ldg_cg4(h0 + b * 512 + kb * 64 + kk)
                    : ldg_cg4(h1 + b * 512 + (kb - 8) * 64 + kk);
                inT[(kk + 0) * 68 + b] = v.x;
                inT[(kk + 1) * 68 + b] = v.y;
                inT[(kk + 2) * 68 + b] = v.z;
                inT[(kk + 3) * 68 + b] = v.w;
            }
            const int r = tid >> 1, kq2 = tid & 1;
            const float* wsrc = W1 + (size_t)(r0 + r) * 1024 + kb * 64 + kq2 * 32;
#pragma unroll
            for (int i = 0; i < 8; ++i)
                *(float4*)&wlds[r * 68 + kq2 * 32 + i * 4] = *(const float4*)(wsrc + i * 4);
            __syncthreads();
            gemm_tile(wlds, inT, z1p + (size_t)kb * 64 * G4H, r0, tid);
        }
        grid_sync(bar, ph++);
    }
}

extern "C" void kernel_launch(void* const* d_in, const int* in_sizes, int n_in,
                              void* d_out, int out_size, void* d_ws, size_t ws_size,
                              hipStream_t stream)
{
    (void)in_sizes; (void)n_in; (void)out_size; (void)ws_size;
    const float* x    = (const float*)d_in[0];
    const float* W0   = (const float*)d_in[1];
    const float* b0   = (const float*)d_in[2];
    const float* lng0 = (const float*)d_in[3];
    const float* lnb0 = (const float*)d_in[4];
    const float* W1   = (const float*)d_in[5];
    const float* b1   = (const float*)d_in[6];
    const float* lng1 = (const float*)d_in[7];
    const float* lnb1 = (const float*)d_in[8];
    const float* hwW  = (const float*)d_in[9];
    const float* hwb  = (const float*)d_in[10];
    float* out = (float*)d_out;
    float* ws  = (float*)d_ws;

    ln_lstm_init_kernel<<<dim3(128), dim3(256), 0, stream>>>(ws);
    LayerNormLSTMStack_55508157333865_kernel<<<dim3(NBLK), dim3(NTHR), 0, stream>>>(
        x, W0, b0, lng0, lnb0, W1, b1, lng1, lnb1, hwW, hwb, out, ws);
}